// Round 1
// baseline (161.790 us; speedup 1.0000x reference)
//
#include <hip/hip_runtime.h>

// Adaptive max pool NHWC (128,57,57,512) f32 -> (128,7,7,512) f32.
// Bins from _split_coefficient(57,7): [8,8,8,8,8,8,9] -> offsets 0,8,...,48,57.
// Disjoint bins => each input element read exactly once; pure HBM-streaming.

#define N_  128
#define H_  57
#define W_  57
#define C_  512
#define OH_ 7
#define OW_ 7
#define C4_ (C_ / 4)   // 128 float4 per spatial position

__global__ __launch_bounds__(128)
void adaptive_maxpool_kernel(const float* __restrict__ x, float* __restrict__ out) {
    // One block per output position (n, oh, ow); 128 threads cover C=512 as float4.
    const int bid = blockIdx.x;
    const int ow  = bid % OW_;
    const int oh  = (bid / OW_) % OH_;
    const int n   = bid / (OW_ * OH_);
    const int c4  = threadIdx.x;           // 0..127, float4 channel index

    const int h0 = oh * 8;
    const int h1 = (oh == OH_ - 1) ? H_ : h0 + 8;
    const int w0 = ow * 8;
    const int w1 = (ow == OW_ - 1) ? W_ : w0 + 8;

    const float4* __restrict__ xin =
        reinterpret_cast<const float4*>(x) + (size_t)n * H_ * W_ * C4_ + c4;

    float4 m = make_float4(-INFINITY, -INFINITY, -INFINITY, -INFINITY);
    for (int h = h0; h < h1; ++h) {
        const float4* row = xin + (size_t)h * W_ * C4_ + (size_t)w0 * C4_;
        #pragma unroll 4
        for (int w = w0; w < w1; ++w) {
            float4 v = *row;
            row += C4_;
            m.x = fmaxf(m.x, v.x);
            m.y = fmaxf(m.y, v.y);
            m.z = fmaxf(m.z, v.z);
            m.w = fmaxf(m.w, v.w);
        }
    }

    float4* o = reinterpret_cast<float4*>(out) + (size_t)bid * C4_ + c4;
    *o = m;
}

extern "C" void kernel_launch(void* const* d_in, const int* in_sizes, int n_in,
                              void* d_out, int out_size, void* d_ws, size_t ws_size,
                              hipStream_t stream) {
    const float* x = (const float*)d_in[0];
    float* out = (float*)d_out;
    const int grid = N_ * OH_ * OW_;   // 6272 blocks
    adaptive_maxpool_kernel<<<grid, 128, 0, stream>>>(x, out);
}